// Round 1
// baseline (3417.302 us; speedup 1.0000x reference)
//
#include <hip/hip_runtime.h>
#include <math.h>

// Problem constants (shapes fixed by setup_inputs: B=1024, N=200000, D=128, K=5)
#define D128 128
#define QT 64        // queries per block (kernel B)
#define KT 64        // keys per LDS subtile
#define NC 2048      // keys per chunk (per-block N extent)
#define TPB 256
#define TOPK 5

// Branch-free descending insert into a register-resident top-5 (constant indices
// only — dynamic indexing would spill the arrays to scratch).
// Precondition: nv > v[4].
__device__ __forceinline__ void insert5(float (&v)[5], int (&idx)[5], float nv, int nj) {
    bool g3 = nv > v[3], g2 = nv > v[2], g1 = nv > v[1], g0 = nv > v[0];
    v[4] = g3 ? v[3] : nv;                 idx[4] = g3 ? idx[3] : nj;
    v[3] = g3 ? (g2 ? v[2] : nv) : v[3];   idx[3] = g3 ? (g2 ? idx[2] : nj) : idx[3];
    v[2] = g2 ? (g1 ? v[1] : nv) : v[2];   idx[2] = g2 ? (g1 ? idx[1] : nj) : idx[2];
    v[1] = g1 ? (g0 ? v[0] : nv) : v[1];   idx[1] = g1 ? (g0 ? idx[0] : nj) : idx[1];
    v[0] = g0 ? nv : v[0];                 idx[0] = g0 ? nj : idx[0];
}

// ---------------- Kernel A: normalize queries ----------------
__global__ void qnorm_kernel(const float* __restrict__ q, float* __restrict__ qn, int B) {
    int b = blockIdx.x;
    int t = threadIdx.x;  // 64 threads, 2 dims each
    float v0 = q[(size_t)b * D128 + t];
    float v1 = q[(size_t)b * D128 + t + 64];
    float ss = v0 * v0 + v1 * v1;
    #pragma unroll
    for (int off = 32; off > 0; off >>= 1) ss += __shfl_xor(ss, off, 64);
    float scale = 1.0f / fmaxf(sqrtf(ss), 1e-12f);
    qn[(size_t)b * D128 + t]      = v0 * scale;
    qn[(size_t)b * D128 + t + 64] = v1 * scale;
}

// ---------------- Kernel B: fused sim + per-chunk top-5 ----------------
// Block: 64 queries x 2048 keys. 256 threads; thread = (query pair qp, key slice ks).
// LDS row stride 33 float4 (132 floats): key reads conflict-free, query reads 2-way (free).
__global__ __launch_bounds__(TPB, 2) void simtopk_kernel(
    const float* __restrict__ qn, const float* __restrict__ mem,
    const int* __restrict__ index_map, const int* __restrict__ excl,
    float* __restrict__ cand_val, int* __restrict__ cand_idx,
    int B, int N, int nchunks)
{
    __shared__ float4 sQ4[QT * 33];   // 33.8 KB
    __shared__ float4 sK4[KT * 33];   // 33.8 KB  -> 2 blocks/CU

    const int chunk = blockIdx.x;
    const int q0 = blockIdx.y * QT;
    const int k0 = chunk * NC;
    const int t = threadIdx.x;
    const int qp = t >> 3;   // 0..31 query pair
    const int ks = t & 7;    // key slice

    const float4* qn4  = (const float4*)qn;
    const float4* mem4 = (const float4*)mem;

    // Stage queries (coalesced, once per block)
    for (int i = t; i < QT * 32; i += TPB) {
        int row = i >> 5, col = i & 31;
        int q = q0 + row;
        float4 v = make_float4(0.f, 0.f, 0.f, 0.f);
        if (q < B) v = qn4[(size_t)q * 32 + col];
        sQ4[row * 33 + col] = v;
    }

    const int qa = q0 + 2 * qp, qb = qa + 1;
    const int ea = (qa < B) ? excl[qa] : -2147483647;
    const int eb = (qb < B) ? excl[qb] : -2147483647;

    float va[5], vb[5]; int ia[5], ib[5];
    #pragma unroll
    for (int i = 0; i < 5; ++i) { va[i] = -INFINITY; vb[i] = -INFINITY; ia[i] = 0; ib[i] = 0; }

    for (int kt = 0; kt < NC; kt += KT) {
        __syncthreads();
        // Stage key subtile (coalesced)
        for (int i = t; i < KT * 32; i += TPB) {
            int row = i >> 5, col = i & 31;
            int j = k0 + kt + row;
            float4 v = make_float4(0.f, 0.f, 0.f, 0.f);
            if (j < N) v = mem4[(size_t)j * 32 + col];
            sK4[row * 33 + col] = v;
        }
        __syncthreads();

        float acc0[8], acc1[8];
        #pragma unroll
        for (int kk = 0; kk < 8; ++kk) { acc0[kk] = 0.f; acc1[kk] = 0.f; }

        #pragma unroll 4
        for (int d4 = 0; d4 < 32; ++d4) {
            float4 a4 = sQ4[(2 * qp) * 33 + d4];
            float4 b4 = sQ4[(2 * qp + 1) * 33 + d4];
            #pragma unroll
            for (int kk = 0; kk < 8; ++kk) {
                float4 kv = sK4[(kk * 8 + ks) * 33 + d4];
                acc0[kk] += a4.x * kv.x + a4.y * kv.y + a4.z * kv.z + a4.w * kv.w;
                acc1[kk] += b4.x * kv.x + b4.y * kv.y + b4.z * kv.z + b4.w * kv.w;
            }
        }

        #pragma unroll
        for (int kk = 0; kk < 8; ++kk) {
            int j = k0 + kt + kk * 8 + ks;
            if (j >= N) continue;
            int im = index_map[j];
            float v0 = acc0[kk];
            if (im != ea && v0 > va[4]) insert5(va, ia, v0, j);
            float v1 = acc1[kk];
            if (im != eb && v1 > vb[4]) insert5(vb, ib, v1, j);
        }
    }

    __syncthreads();
    // Merge the 8 key-slices per query through LDS (reuse sK4 space).
    float* mv = (float*)sK4;            // 64*40 floats
    int*   mi = (int*)((float*)sK4 + 2560);
    #pragma unroll
    for (int i = 0; i < 5; ++i) {
        mv[(2 * qp) * 40 + ks * 5 + i] = va[i];
        mi[(2 * qp) * 40 + ks * 5 + i] = ia[i];
        mv[(2 * qp + 1) * 40 + ks * 5 + i] = vb[i];
        mi[(2 * qp + 1) * 40 + ks * 5 + i] = ib[i];
    }
    __syncthreads();
    if (ks < 2) {
        int qloc = 2 * qp + ks;
        int q = q0 + qloc;
        if (q < B) {
            float fv[5]; int fi[5];
            #pragma unroll
            for (int i = 0; i < 5; ++i) { fv[i] = -INFINITY; fi[i] = 0; }
            for (int s = 0; s < 8; ++s) {
                #pragma unroll
                for (int i = 0; i < 5; ++i) {
                    float v = mv[qloc * 40 + s * 5 + i];
                    if (v > fv[4]) insert5(fv, fi, v, mi[qloc * 40 + s * 5 + i]);
                }
            }
            size_t base = ((size_t)q * nchunks + chunk) * 5;
            #pragma unroll
            for (int i = 0; i < 5; ++i) { cand_val[base + i] = fv[i]; cand_idx[base + i] = fi[i]; }
        }
    }
}

// ---------------- Kernel C: merge chunks + softmax + gather + normalize ----------------
__global__ void finalize_kernel(const float* __restrict__ cand_val, const int* __restrict__ cand_idx,
                                const float* __restrict__ mem, float* __restrict__ outR,
                                float* __restrict__ outD, float* __restrict__ outW, int nchunks)
{
    int q = blockIdx.x;
    int t = threadIdx.x;  // 64 threads = 1 wave
    int ncand = nchunks * TOPK;

    float lv[5]; int li[5];
    #pragma unroll
    for (int i = 0; i < 5; ++i) { lv[i] = -INFINITY; li[i] = 0; }
    const float* cv = cand_val + (size_t)q * ncand;
    const int*   ci = cand_idx + (size_t)q * ncand;
    for (int i = t; i < ncand; i += 64) {
        float v = cv[i];
        if (v > lv[4]) insert5(lv, li, v, ci[i]);
    }

    __shared__ float sV[64 * 5];
    __shared__ int   sI[64 * 5];
    __shared__ float sW[5];
    __shared__ int   sJ[5];
    #pragma unroll
    for (int i = 0; i < 5; ++i) { sV[t * 5 + i] = lv[i]; sI[t * 5 + i] = li[i]; }
    __syncthreads();
    if (t == 0) {
        float fv[5]; int fi[5];
        #pragma unroll
        for (int i = 0; i < 5; ++i) { fv[i] = -INFINITY; fi[i] = 0; }
        for (int s = 0; s < 64; ++s) {
            #pragma unroll
            for (int i = 0; i < 5; ++i) {
                float v = sV[s * 5 + i];
                if (v > fv[4]) insert5(fv, fi, v, sI[s * 5 + i]);
            }
        }
        float m = fv[0];
        float e[5], sum = 0.f;
        #pragma unroll
        for (int i = 0; i < 5; ++i) { e[i] = expf((fv[i] - m) * 10.0f); sum += e[i]; }
        float inv = 1.0f / sum;
        #pragma unroll
        for (int i = 0; i < 5; ++i) { float w = e[i] * inv; sW[i] = w; sJ[i] = fi[i]; outW[(size_t)q * 5 + i] = w; }
        outD[q] = 1.0f - fv[0];
    }
    __syncthreads();
    float r0 = 0.f, r1 = 0.f;
    #pragma unroll
    for (int k = 0; k < 5; ++k) {
        const float* mrow = mem + (size_t)sJ[k] * D128;
        r0 += sW[k] * mrow[t];
        r1 += sW[k] * mrow[t + 64];
    }
    float ss = r0 * r0 + r1 * r1;
    #pragma unroll
    for (int off = 32; off > 0; off >>= 1) ss += __shfl_xor(ss, off, 64);
    float scale = 1.0f / fmaxf(sqrtf(ss), 1e-12f);
    outR[(size_t)q * D128 + t]      = r0 * scale;
    outR[(size_t)q * D128 + t + 64] = r1 * scale;
}

extern "C" void kernel_launch(void* const* d_in, const int* in_sizes, int n_in,
                              void* d_out, int out_size, void* d_ws, size_t ws_size,
                              hipStream_t stream) {
    const float* query  = (const float*)d_in[0];   // [B,128] fp32
    const float* memory = (const float*)d_in[1];   // [N,128] fp32 (pre-normalized)
    const int* index_map = (const int*)d_in[2];    // [N] int32
    const int* excl      = (const int*)d_in[3];    // [B] int32

    const int B = in_sizes[3];
    const int N = in_sizes[2];
    const int nchunks = (N + NC - 1) / NC;

    // Workspace: qn [B*128] | cand_val [B*nchunks*5] | cand_idx [B*nchunks*5]  (~4.6 MB)
    float* qn       = (float*)d_ws;
    float* cand_val = qn + (size_t)B * D128;
    int*   cand_idx = (int*)(cand_val + (size_t)B * nchunks * TOPK);

    float* outR = (float*)d_out;                   // [B,128]
    float* outD = outR + (size_t)B * D128;         // [B]
    float* outW = outD + B;                        // [B,5]

    qnorm_kernel<<<B, 64, 0, stream>>>(query, qn, B);
    dim3 gridB(nchunks, (B + QT - 1) / QT);
    simtopk_kernel<<<gridB, TPB, 0, stream>>>(qn, memory, index_map, excl,
                                              cand_val, cand_idx, B, N, nchunks);
    finalize_kernel<<<B, 64, 0, stream>>>(cand_val, cand_idx, memory, outR, outD, outW, nchunks);
}

// Round 2
// 675.777 us; speedup vs baseline: 5.0569x; 5.0569x over previous
//
#include <hip/hip_runtime.h>
#include <math.h>

// Shapes fixed by setup_inputs: B=1024, N=200000, D=128, K=5
#define D128 128
#define TOPK 5
#define KC 256          // key chunks
#define CHUNK 784       // keys per chunk; KC*CHUNK = 200704 = NP (padded N)
#define NP 200704
#define NTILES 49       // CHUNK/16
#define CPC 6           // candidates kept per (query, chunk) — top-6 for exclusion margin
#define MERGE_M 8       // rescored candidates per query

typedef __attribute__((ext_vector_type(8))) short short8;   // 8 bf16 = 4 VGPR
typedef __attribute__((ext_vector_type(4))) float f32x4;    // MFMA acc

// round-to-nearest-even float -> bf16
__device__ __forceinline__ short f2bf(float f) {
    union { float f; unsigned u; } c; c.f = f;
    unsigned u = c.u + 0x7FFFu + ((c.u >> 16) & 1u);
    return (short)(u >> 16);
}

// Guarded branch-free descending insert (no-op when nv <= v[NN-1]); constant
// indices after unroll so arrays stay in VGPRs.
template <int NN>
__device__ __forceinline__ void insertg(float (&v)[NN], int (&x)[NN], float nv, int nj) {
    bool g[NN];
    #pragma unroll
    for (int i = 0; i < NN; ++i) g[i] = nv > v[i];
    #pragma unroll
    for (int i = NN - 1; i > 0; --i) {
        v[i] = g[i - 1] ? v[i - 1] : (g[i] ? nv : v[i]);
        x[i] = g[i - 1] ? x[i - 1] : (g[i] ? nj : x[i]);
    }
    v[0] = g[0] ? nv : v[0];
    x[0] = g[0] ? nj : x[0];
}

// ---------------- Kernel A: normalize queries -> fp32 qn + bf16 qbf ----------------
__global__ void qnorm_kernel(const float* __restrict__ q, float* __restrict__ qn,
                             short* __restrict__ qbf) {
    int b = blockIdx.x, t = threadIdx.x;   // 64 threads
    float v0 = q[(size_t)b * D128 + t];
    float v1 = q[(size_t)b * D128 + t + 64];
    float ss = v0 * v0 + v1 * v1;
    #pragma unroll
    for (int off = 32; off > 0; off >>= 1) ss += __shfl_xor(ss, off, 64);
    float scale = 1.0f / fmaxf(sqrtf(ss), 1e-12f);
    float a0 = v0 * scale, a1 = v1 * scale;
    qn[(size_t)b * D128 + t] = a0;
    qn[(size_t)b * D128 + t + 64] = a1;
    qbf[(size_t)b * D128 + t] = f2bf(a0);
    qbf[(size_t)b * D128 + t + 64] = f2bf(a1);
}

// ---------------- Kernel B: memory fp32 -> bf16, zero-padded to NP rows ----------------
__global__ void mconv_kernel(const float* __restrict__ mem, short* __restrict__ mbf, int N) {
    int idx = blockIdx.x * 256 + threadIdx.x;     // one short8 (8 elems) per thread
    if (idx >= NP * 16) return;
    int row = idx >> 4, seg = idx & 15;
    short8 out;
    if (row < N) {
        const float* p = mem + (size_t)row * D128 + seg * 8;
        #pragma unroll
        for (int i = 0; i < 8; ++i) out[i] = f2bf(p[i]);
    } else {
        #pragma unroll
        for (int i = 0; i < 8; ++i) out[i] = 0;
    }
    *(short8*)(mbf + (size_t)row * D128 + seg * 8) = out;
}

// ---------------- Kernel C: MFMA sim sweep + per-chunk top-6 ----------------
// Block = 1 wave (64 threads) = 64 queries (4 q-tiles of 16) x one 784-key chunk.
// Orientation: C[row=key][col=query] so each lane owns ONE query per q-tile:
//   A operand = keys  (A[m=lane&15][k=quad*8+j]), B operand = queries,
//   C: col(query)=lane&15, row(key)=quad*4+reg.
__global__ void simtopk_mfma(const short* __restrict__ qbf, const short* __restrict__ mbf,
                             float* __restrict__ cand_val, int* __restrict__ cand_idx) {
    const int qg = blockIdx.x;       // 0..15  (query group of 64)
    const int chunk = blockIdx.y;    // 0..KC-1
    const int lane = threadIdx.x;
    const int n = lane & 15;         // query col within tile / key row for A loads
    const int quad = lane >> 4;

    // Resident B-frags: 4 q-tiles x 4 K-steps
    short8 bq[4][4];
    #pragma unroll
    for (int f = 0; f < 4; ++f) {
        const short* qrow = qbf + (size_t)(qg * 64 + f * 16 + n) * D128 + quad * 8;
        #pragma unroll
        for (int s = 0; s < 4; ++s) bq[f][s] = *(const short8*)(qrow + s * 32);
    }

    float lv[4][CPC]; int li[4][CPC];
    #pragma unroll
    for (int f = 0; f < 4; ++f)
        #pragma unroll
        for (int e = 0; e < CPC; ++e) { lv[f][e] = -3.0e38f; li[f][e] = 0; }

    const int kbase0 = chunk * CHUNK;
    const short* aptr = mbf + ((size_t)kbase0 + n) * D128 + quad * 8;

    for (int t = 0; t < NTILES; ++t) {
        short8 a0 = *(const short8*)(aptr);
        short8 a1 = *(const short8*)(aptr + 32);
        short8 a2 = *(const short8*)(aptr + 64);
        short8 a3 = *(const short8*)(aptr + 96);
        aptr += 16 * D128;

        f32x4 c0 = {0.f, 0.f, 0.f, 0.f}, c1 = c0, c2 = c0, c3 = c0;
        c0 = __builtin_amdgcn_mfma_f32_16x16x32_bf16(a0, bq[0][0], c0, 0, 0, 0);
        c1 = __builtin_amdgcn_mfma_f32_16x16x32_bf16(a0, bq[1][0], c1, 0, 0, 0);
        c2 = __builtin_amdgcn_mfma_f32_16x16x32_bf16(a0, bq[2][0], c2, 0, 0, 0);
        c3 = __builtin_amdgcn_mfma_f32_16x16x32_bf16(a0, bq[3][0], c3, 0, 0, 0);
        c0 = __builtin_amdgcn_mfma_f32_16x16x32_bf16(a1, bq[0][1], c0, 0, 0, 0);
        c1 = __builtin_amdgcn_mfma_f32_16x16x32_bf16(a1, bq[1][1], c1, 0, 0, 0);
        c2 = __builtin_amdgcn_mfma_f32_16x16x32_bf16(a1, bq[2][1], c2, 0, 0, 0);
        c3 = __builtin_amdgcn_mfma_f32_16x16x32_bf16(a1, bq[3][1], c3, 0, 0, 0);
        c0 = __builtin_amdgcn_mfma_f32_16x16x32_bf16(a2, bq[0][2], c0, 0, 0, 0);
        c1 = __builtin_amdgcn_mfma_f32_16x16x32_bf16(a2, bq[1][2], c1, 0, 0, 0);
        c2 = __builtin_amdgcn_mfma_f32_16x16x32_bf16(a2, bq[2][2], c2, 0, 0, 0);
        c3 = __builtin_amdgcn_mfma_f32_16x16x32_bf16(a2, bq[3][2], c3, 0, 0, 0);
        c0 = __builtin_amdgcn_mfma_f32_16x16x32_bf16(a3, bq[0][3], c0, 0, 0, 0);
        c1 = __builtin_amdgcn_mfma_f32_16x16x32_bf16(a3, bq[1][3], c1, 0, 0, 0);
        c2 = __builtin_amdgcn_mfma_f32_16x16x32_bf16(a3, bq[2][3], c2, 0, 0, 0);
        c3 = __builtin_amdgcn_mfma_f32_16x16x32_bf16(a3, bq[3][3], c3, 0, 0, 0);

        const int kb = kbase0 + t * 16 + quad * 4;
        #pragma unroll
        for (int r = 0; r < 4; ++r) {
            float v;
            v = c0[r]; if (__any(v > lv[0][CPC - 1])) insertg<CPC>(lv[0], li[0], v, kb + r);
            v = c1[r]; if (__any(v > lv[1][CPC - 1])) insertg<CPC>(lv[1], li[1], v, kb + r);
            v = c2[r]; if (__any(v > lv[2][CPC - 1])) insertg<CPC>(lv[2], li[2], v, kb + r);
            v = c3[r]; if (__any(v > lv[3][CPC - 1])) insertg<CPC>(lv[3], li[3], v, kb + r);
        }
    }

    // Merge the 4 quads (which partition keys) per query via LDS.
    __shared__ float sv[64 * 4 * CPC];
    __shared__ int   si[64 * 4 * CPC];
    #pragma unroll
    for (int f = 0; f < 4; ++f)
        #pragma unroll
        for (int e = 0; e < CPC; ++e) {
            sv[(lane * 4 + f) * CPC + e] = lv[f][e];
            si[(lane * 4 + f) * CPC + e] = li[f][e];
        }
    __syncthreads();
    // merger lane handles (f = lane>>4, q = lane&15): 4 source lanes Q*16+q, list f
    {
        const int f = lane >> 4, qq = lane & 15;
        float mv[CPC]; int mi[CPC];
        #pragma unroll
        for (int e = 0; e < CPC; ++e) { mv[e] = -3.0e38f; mi[e] = 0; }
        for (int Q = 0; Q < 4; ++Q) {
            int src = (Q * 16 + qq) * 4 + f;
            #pragma unroll
            for (int e = 0; e < CPC; ++e) {
                float v = sv[src * CPC + e];
                if (v > mv[CPC - 1]) insertg<CPC>(mv, mi, v, si[src * CPC + e]);
            }
        }
        int qglob = qg * 64 + f * 16 + qq;
        size_t base = ((size_t)qglob * KC + chunk) * CPC;
        #pragma unroll
        for (int e = 0; e < CPC; ++e) { cand_val[base + e] = mv[e]; cand_idx[base + e] = mi[e]; }
    }
}

// ---------------- Kernel D: merge chunks, filter, fp32 rescore, outputs ----------------
__global__ void finalize_kernel(const float* __restrict__ cand_val, const int* __restrict__ cand_idx,
                                const float* __restrict__ mem, const float* __restrict__ qn,
                                const int* __restrict__ index_map, const int* __restrict__ excl,
                                float* __restrict__ outR, float* __restrict__ outD,
                                float* __restrict__ outW, int N) {
    const int q = blockIdx.x, lane = threadIdx.x;
    const int NCAND = KC * CPC;

    float lv[MERGE_M]; int li[MERGE_M];
    #pragma unroll
    for (int e = 0; e < MERGE_M; ++e) { lv[e] = -3.0e38f; li[e] = -1; }
    size_t base = (size_t)q * NCAND;
    for (int i = lane; i < NCAND; i += 64) {
        float v = cand_val[base + i];
        if (v > lv[MERGE_M - 1]) insertg<MERGE_M>(lv, li, v, cand_idx[base + i]);
    }

    __shared__ float sv[64 * MERGE_M];
    __shared__ int   si[64 * MERGE_M];
    __shared__ int   sIdx[MERGE_M];
    __shared__ int   sCnt;
    __shared__ float sEx[MERGE_M];
    __shared__ float sW[TOPK];
    __shared__ int   sJ[TOPK];
    #pragma unroll
    for (int e = 0; e < MERGE_M; ++e) { sv[lane * MERGE_M + e] = lv[e]; si[lane * MERGE_M + e] = li[e]; }
    __syncthreads();

    if (lane == 0) {
        float mv[MERGE_M]; int mi[MERGE_M];
        #pragma unroll
        for (int e = 0; e < MERGE_M; ++e) { mv[e] = -3.0e38f; mi[e] = -1; }
        for (int j = 0; j < 64 * MERGE_M; ++j) {
            float v = sv[j];
            if (v > mv[MERGE_M - 1]) insertg<MERGE_M>(mv, mi, v, si[j]);
        }
        int e = excl[q];
        int cnt = 0;
        for (int j = 0; j < MERGE_M; ++j) {
            int id = mi[j];
            if (id >= 0 && id < N && mv[j] > -1.0e30f && index_map[id] != e)
                sIdx[cnt++] = id;
        }
        sCnt = cnt;
    }
    __syncthreads();

    // exact fp32 rescore of surviving candidates
    int cnt = sCnt;
    float q0 = qn[(size_t)q * D128 + lane];
    float q1 = qn[(size_t)q * D128 + lane + 64];
    for (int j = 0; j < cnt; ++j) {
        const float* mrow = mem + (size_t)sIdx[j] * D128;
        float p = q0 * mrow[lane] + q1 * mrow[lane + 64];
        #pragma unroll
        for (int off = 32; off > 0; off >>= 1) p += __shfl_xor(p, off, 64);
        if (lane == 0) sEx[j] = p;
    }
    __syncthreads();

    if (lane == 0) {
        float bv[TOPK]; int bi[TOPK];
        #pragma unroll
        for (int e = 0; e < TOPK; ++e) { bv[e] = -3.0e38f; bi[e] = 0; }
        for (int j = 0; j < cnt; ++j)
            if (sEx[j] > bv[TOPK - 1]) insertg<TOPK>(bv, bi, sEx[j], sIdx[j]);
        float m = bv[0], ex[TOPK], sum = 0.f;
        #pragma unroll
        for (int k = 0; k < TOPK; ++k) { ex[k] = __expf((bv[k] - m) * 10.0f); sum += ex[k]; }
        float inv = 1.0f / sum;
        #pragma unroll
        for (int k = 0; k < TOPK; ++k) {
            float w = ex[k] * inv;
            sW[k] = w; sJ[k] = bi[k];
            outW[(size_t)q * TOPK + k] = w;
        }
        outD[q] = 1.0f - bv[0];
    }
    __syncthreads();

    float r0 = 0.f, r1 = 0.f;
    #pragma unroll
    for (int k = 0; k < TOPK; ++k) {
        const float* mrow = mem + (size_t)sJ[k] * D128;
        r0 += sW[k] * mrow[lane];
        r1 += sW[k] * mrow[lane + 64];
    }
    float ss = r0 * r0 + r1 * r1;
    #pragma unroll
    for (int off = 32; off > 0; off >>= 1) ss += __shfl_xor(ss, off, 64);
    float scale = 1.0f / fmaxf(sqrtf(ss), 1e-12f);
    outR[(size_t)q * D128 + lane] = r0 * scale;
    outR[(size_t)q * D128 + lane + 64] = r1 * scale;
}

extern "C" void kernel_launch(void* const* d_in, const int* in_sizes, int n_in,
                              void* d_out, int out_size, void* d_ws, size_t ws_size,
                              hipStream_t stream) {
    const float* query  = (const float*)d_in[0];   // [B,128] fp32
    const float* memory = (const float*)d_in[1];   // [N,128] fp32 (pre-normalized)
    const int* index_map = (const int*)d_in[2];    // [N] int32 (arange)
    const int* excl      = (const int*)d_in[3];    // [B] int32

    const int B = in_sizes[3];                     // 1024
    const int N = in_sizes[2];                     // 200000

    // Workspace layout (16B-aligned segments):
    //   qn   fp32 [B*128]        @ 0         (512 KB)
    //   qbf  bf16 [B*128]        @ 524288    (256 KB)
    //   mbf  bf16 [NP*128]       @ 786432    (51.4 MB)
    //   cand_val fp32 [B*KC*6]   @ 52166656  (6.3 MB)
    //   cand_idx i32  [B*KC*6]   @ 58458112  (6.3 MB)   total ~61.8 MB
    char* ws = (char*)d_ws;
    float* qn       = (float*)(ws);
    short* qbf      = (short*)(ws + 524288);
    short* mbf      = (short*)(ws + 786432);
    float* cand_val = (float*)(ws + 52166656);
    int*   cand_idx = (int*)(ws + 58458112);

    float* outR = (float*)d_out;                   // [B,128]
    float* outD = outR + (size_t)B * D128;         // [B]
    float* outW = outD + B;                        // [B,5]

    qnorm_kernel<<<B, 64, 0, stream>>>(query, qn, qbf);
    mconv_kernel<<<(NP * 16 + 255) / 256, 256, 0, stream>>>(memory, mbf, N);
    dim3 gridC(B / 64, KC);   // x = query-group (consecutive blocks share the key chunk)
    simtopk_mfma<<<gridC, 64, 0, stream>>>(qbf, mbf, cand_val, cand_idx);
    finalize_kernel<<<B, 64, 0, stream>>>(cand_val, cand_idx, memory, qn,
                                          index_map, excl, outR, outD, outW, N);
}

// Round 3
// 342.214 us; speedup vs baseline: 9.9859x; 1.9747x over previous
//
#include <hip/hip_runtime.h>
#include <math.h>

// Shapes fixed by setup_inputs: B=1024, N=200000, D=128, K=5
#define D128 128
#define TOPK 5
#define NP 200704        // N padded to 64
#define NCHUNK 3136      // NP/64 (64-key chunks)
#define NSTRIP 392       // NP/512 (512-key strips per pass-A block)
#define MARGIN 0.008f    // bf16-sim + fp16-storage error bound (<=2.8e-3) + slack

typedef __attribute__((ext_vector_type(8))) short short8;   // 8 bf16 = 4 VGPR
typedef __attribute__((ext_vector_type(4))) float f32x4;    // MFMA acc

__device__ __forceinline__ short f2bf(float f) {
    union { float f; unsigned u; } c; c.f = f;
    unsigned u = c.u + 0x7FFFu + ((c.u >> 16) & 1u);
    return (short)(u >> 16);
}

// Guarded branch-free descending insert; constant indices after unroll.
// Precondition: nv > v[NN-1].
template <int NN>
__device__ __forceinline__ void insertg(float (&v)[NN], int (&x)[NN], float nv, int nj) {
    bool g[NN];
    #pragma unroll
    for (int i = 0; i < NN; ++i) g[i] = nv > v[i];
    #pragma unroll
    for (int i = NN - 1; i > 0; --i) {
        v[i] = g[i - 1] ? v[i - 1] : (g[i] ? nv : v[i]);
        x[i] = g[i - 1] ? x[i - 1] : (g[i] ? nj : x[i]);
    }
    v[0] = g[0] ? nv : v[0];
    x[0] = g[0] ? nj : x[0];
}

// ---------------- Kernel A: normalize queries -> fp32 qn + bf16 qbf ----------------
__global__ void qnorm_kernel(const float* __restrict__ q, float* __restrict__ qn,
                             short* __restrict__ qbf) {
    int b = blockIdx.x, t = threadIdx.x;   // 64 threads
    float v0 = q[(size_t)b * D128 + t];
    float v1 = q[(size_t)b * D128 + t + 64];
    float ss = v0 * v0 + v1 * v1;
    #pragma unroll
    for (int off = 32; off > 0; off >>= 1) ss += __shfl_xor(ss, off, 64);
    float scale = 1.0f / fmaxf(sqrtf(ss), 1e-12f);
    float a0 = v0 * scale, a1 = v1 * scale;
    qn[(size_t)b * D128 + t] = a0;
    qn[(size_t)b * D128 + t + 64] = a1;
    qbf[(size_t)b * D128 + t] = f2bf(a0);
    qbf[(size_t)b * D128 + t + 64] = f2bf(a1);
}

// ---------------- Kernel B: memory fp32 -> bf16, zero-padded to NP rows ----------------
__global__ void mconv_kernel(const float* __restrict__ mem, short* __restrict__ mbf, int N) {
    int idx = blockIdx.x * 256 + threadIdx.x;     // one short8 per thread
    if (idx >= NP * 16) return;
    int row = idx >> 4, seg = idx & 15;
    short8 out;
    if (row < N) {
        const float* p = mem + (size_t)row * D128 + seg * 8;
        #pragma unroll
        for (int i = 0; i < 8; ++i) out[i] = f2bf(p[i]);
    } else {
        #pragma unroll
        for (int i = 0; i < 8; ++i) out[i] = 0;
    }
    *(short8*)(mbf + (size_t)row * D128 + seg * 8) = out;
}

#define MFMA16(a, b, c) __builtin_amdgcn_mfma_f32_16x16x32_bf16(a, b, c, 0, 0, 0)

// ---------------- Kernel C: MFMA sweep, per-(query, 64-key-chunk) running max ----------------
// Block = 4 waves x 64 queries = 256 queries; keys staged in LDS (shared by waves).
// Orientation C[key][query]: lane owns query col n=lane&15 per q-tile; rows quad*4+r.
__global__ __launch_bounds__(256, 4) void simtopk_max(
    const short* __restrict__ qbf, const short* __restrict__ mbf,
    _Float16* __restrict__ cand) {
    __shared__ short sK[64 * 136];   // 64 key rows, 272B stride (pad: conflict-free)
    const int strip = blockIdx.x;    // 0..391, 512 keys each
    const int qsg = blockIdx.y;      // 0..3
    const int t = threadIdx.x, w = t >> 6, lane = t & 63;
    const int n = lane & 15, quad = lane >> 4;
    const int qbase = qsg * 256 + w * 64;

    // Resident B-frags: 4 q-tiles x 4 K-steps (64 VGPR)
    short8 bq[4][4];
    #pragma unroll
    for (int f = 0; f < 4; ++f) {
        const short* qrow = qbf + (size_t)(qbase + f * 16 + n) * D128 + quad * 8;
        #pragma unroll
        for (int s = 0; s < 4; ++s) bq[f][s] = *(const short8*)(qrow + s * 32);
    }

    const size_t k0 = (size_t)strip * 512;
    for (int round = 0; round < 8; ++round) {
        __syncthreads();   // previous round's readers done
        #pragma unroll
        for (int j = 0; j < 4; ++j) {
            int g = j * 256 + t, row = g >> 4, u = g & 15;
            short8 v = *(const short8*)(mbf + (k0 + (size_t)round * 64 + row) * D128 + u * 8);
            *(short8*)(&sK[row * 136 + u * 8]) = v;
        }
        __syncthreads();

        float m0 = -3e38f, m1 = -3e38f, m2 = -3e38f, m3 = -3e38f;
        #pragma unroll
        for (int tt = 0; tt < 4; ++tt) {
            const short* ab = &sK[(tt * 16 + n) * 136 + quad * 8];
            short8 a0 = *(const short8*)(ab);
            short8 a1 = *(const short8*)(ab + 32);
            short8 a2 = *(const short8*)(ab + 64);
            short8 a3 = *(const short8*)(ab + 96);
            f32x4 c0 = {0.f, 0.f, 0.f, 0.f}, c1 = c0, c2 = c0, c3 = c0;
            c0 = MFMA16(a0, bq[0][0], c0);
            c1 = MFMA16(a0, bq[1][0], c1);
            c2 = MFMA16(a0, bq[2][0], c2);
            c3 = MFMA16(a0, bq[3][0], c3);
            c0 = MFMA16(a1, bq[0][1], c0);
            c1 = MFMA16(a1, bq[1][1], c1);
            c2 = MFMA16(a1, bq[2][1], c2);
            c3 = MFMA16(a1, bq[3][1], c3);
            c0 = MFMA16(a2, bq[0][2], c0);
            c1 = MFMA16(a2, bq[1][2], c1);
            c2 = MFMA16(a2, bq[2][2], c2);
            c3 = MFMA16(a2, bq[3][2], c3);
            c0 = MFMA16(a3, bq[0][3], c0);
            c1 = MFMA16(a3, bq[1][3], c1);
            c2 = MFMA16(a3, bq[2][3], c2);
            c3 = MFMA16(a3, bq[3][3], c3);
            m0 = fmaxf(m0, fmaxf(fmaxf(c0[0], c0[1]), fmaxf(c0[2], c0[3])));
            m1 = fmaxf(m1, fmaxf(fmaxf(c1[0], c1[1]), fmaxf(c1[2], c1[3])));
            m2 = fmaxf(m2, fmaxf(fmaxf(c2[0], c2[1]), fmaxf(c2[2], c2[3])));
            m3 = fmaxf(m3, fmaxf(fmaxf(c3[0], c3[1]), fmaxf(c3[2], c3[3])));
        }
        // merge the 4 quads (key partitions) per query
        m0 = fmaxf(m0, __shfl_xor(m0, 16, 64)); m0 = fmaxf(m0, __shfl_xor(m0, 32, 64));
        m1 = fmaxf(m1, __shfl_xor(m1, 16, 64)); m1 = fmaxf(m1, __shfl_xor(m1, 32, 64));
        m2 = fmaxf(m2, __shfl_xor(m2, 16, 64)); m2 = fmaxf(m2, __shfl_xor(m2, 32, 64));
        m3 = fmaxf(m3, __shfl_xor(m3, 16, 64)); m3 = fmaxf(m3, __shfl_xor(m3, 32, 64));
        if (quad == 0) {
            int chunk = strip * 8 + round;
            _Float16* dst = cand + (size_t)chunk * 1024 + qbase;
            dst[n]      = (_Float16)m0;
            dst[16 + n] = (_Float16)m1;
            dst[32 + n] = (_Float16)m2;
            dst[48 + n] = (_Float16)m3;
        }
    }
}

// ---------------- Kernel D: iterative exact selection + outputs ----------------
// One wave per query. Repeatedly recompute (fp32-exact) the chunk with the largest
// stored max; stop when next max + MARGIN <= current 5th best.
__global__ void finalize_select(const _Float16* __restrict__ cand,
                                const float* __restrict__ mem,
                                const float* __restrict__ qn,
                                const int* __restrict__ index_map,
                                const int* __restrict__ excl,
                                float* __restrict__ outR, float* __restrict__ outD,
                                float* __restrict__ outW, int N) {
    const int q = blockIdx.x, lane = threadIdx.x;
    __shared__ float sM[NCHUNK];
    __shared__ float sQ[D128];
    sQ[lane] = qn[(size_t)q * D128 + lane];
    sQ[lane + 64] = qn[(size_t)q * D128 + lane + 64];
    for (int i = lane; i < NCHUNK; i += 64)
        sM[i] = (float)cand[(size_t)i * 1024 + q];
    __syncthreads();

    // per-lane pre-max over its contiguous 49 chunks (3136 = 64*49)
    float lm = -3e38f; int lc = lane * 49;
    for (int j = 0; j < 49; ++j) {
        float v = sM[lane * 49 + j];
        if (v > lm) { lm = v; lc = lane * 49 + j; }
    }

    const int exq = excl[q];
    float t5v[TOPK]; int t5i[TOPK];
    #pragma unroll
    for (int i = 0; i < TOPK; ++i) { t5v[i] = -3e38f; t5i[i] = 0; }

    for (int it = 0; it < NCHUNK; ++it) {
        // wave argmax of (lm, lc), deterministic tie-break
        float bv = lm; int bc = lc;
        #pragma unroll
        for (int off = 32; off > 0; off >>= 1) {
            float ov = __shfl_xor(bv, off, 64);
            int   oc = __shfl_xor(bc, off, 64);
            if (ov > bv || (ov == bv && oc < bc)) { bv = ov; bc = oc; }
        }
        if (bv + MARGIN <= t5v[TOPK - 1]) break;

        if (lane == 0) sM[bc] = -3e38f;
        __syncthreads();
        if (lane == bc / 49) {   // owner rescans its 49
            lm = -3e38f; lc = lane * 49;
            for (int j = 0; j < 49; ++j) {
                float v = sM[lane * 49 + j];
                if (v > lm) { lm = v; lc = lane * 49 + j; }
            }
        }

        // fp32-exact recompute of chunk bc (one key per lane)
        int key = bc * 64 + lane;
        bool valid = (key < N) && (index_map[key] != exq);
        float acc = 0.f;
        if (valid) {
            const float4* mr = (const float4*)(mem + (size_t)key * D128);
            const float4* qv4 = (const float4*)sQ;
            #pragma unroll
            for (int d = 0; d < 32; ++d) {
                float4 a = mr[d], b = qv4[d];
                acc += a.x * b.x + a.y * b.y + a.z * b.z + a.w * b.w;
            }
        }
        float v = valid ? acc : -3e38f;
        // extract up to 5 best of this chunk into running top-5
        #pragma unroll
        for (int r = 0; r < TOPK; ++r) {
            float cv = v; int ck = key;
            #pragma unroll
            for (int off = 32; off > 0; off >>= 1) {
                float ov = __shfl_xor(cv, off, 64);
                int   ok = __shfl_xor(ck, off, 64);
                if (ov > cv || (ov == cv && ok < ck)) { cv = ov; ck = ok; }
            }
            if (cv <= t5v[TOPK - 1]) break;
            insertg<TOPK>(t5v, t5i, cv, ck);
            if (key == ck) v = -3e38f;
        }
    }

    // outputs — t5v/t5i are wave-uniform, fp32-exact
    float mx = t5v[0], ex[TOPK], sum = 0.f;
    #pragma unroll
    for (int k = 0; k < TOPK; ++k) { ex[k] = __expf((t5v[k] - mx) * 10.0f); sum += ex[k]; }
    float inv = 1.0f / sum;
    if (lane == 0) {
        #pragma unroll
        for (int k = 0; k < TOPK; ++k) outW[(size_t)q * TOPK + k] = ex[k] * inv;
        outD[q] = 1.0f - t5v[0];
    }
    float r0 = 0.f, r1 = 0.f;
    #pragma unroll
    for (int k = 0; k < TOPK; ++k) {
        const float* mr = mem + (size_t)t5i[k] * D128;
        float wk = ex[k] * inv;
        r0 += wk * mr[lane];
        r1 += wk * mr[lane + 64];
    }
    float ss = r0 * r0 + r1 * r1;
    #pragma unroll
    for (int off = 32; off > 0; off >>= 1) ss += __shfl_xor(ss, off, 64);
    float scale = 1.0f / fmaxf(sqrtf(ss), 1e-12f);
    outR[(size_t)q * D128 + lane] = r0 * scale;
    outR[(size_t)q * D128 + lane + 64] = r1 * scale;
}

extern "C" void kernel_launch(void* const* d_in, const int* in_sizes, int n_in,
                              void* d_out, int out_size, void* d_ws, size_t ws_size,
                              hipStream_t stream) {
    const float* query  = (const float*)d_in[0];   // [B,128] fp32
    const float* memory = (const float*)d_in[1];   // [N,128] fp32 (pre-normalized)
    const int* index_map = (const int*)d_in[2];    // [N] int32
    const int* excl      = (const int*)d_in[3];    // [B] int32

    const int B = in_sizes[3];                     // 1024
    const int N = in_sizes[2];                     // 200000

    // Workspace:
    //   qn   fp32 [B*128]          @ 0          (512 KB)
    //   qbf  bf16 [B*128]          @ 524288     (256 KB)
    //   mbf  bf16 [NP*128]         @ 786432     (51.4 MB)
    //   cand fp16 [NCHUNK*1024]    @ 52166656   (6.42 MB)  total ~58.6 MB
    char* ws = (char*)d_ws;
    float*    qn   = (float*)(ws);
    short*    qbf  = (short*)(ws + 524288);
    short*    mbf  = (short*)(ws + 786432);
    _Float16* cand = (_Float16*)(ws + 52166656);

    float* outR = (float*)d_out;                   // [B,128]
    float* outD = outR + (size_t)B * D128;         // [B]
    float* outW = outD + B;                        // [B,5]

    qnorm_kernel<<<B, 64, 0, stream>>>(query, qn, qbf);
    mconv_kernel<<<(NP * 16 + 255) / 256, 256, 0, stream>>>(memory, mbf, N);
    dim3 gridC(NSTRIP, 4);
    simtopk_max<<<gridC, 256, 0, stream>>>(qbf, mbf, cand);
    finalize_select<<<B, 64, 0, stream>>>(cand, memory, qn, index_map, excl,
                                          outR, outD, outW, N);
}

// Round 4
// 331.618 us; speedup vs baseline: 10.3049x; 1.0320x over previous
//
#include <hip/hip_runtime.h>
#include <math.h>

// Shapes fixed by setup_inputs: B=1024, N=200000, D=128, K=5
#define D128 128
#define TOPK 5
#define NP 200704        // N padded to 64
#define NCHUNK 3136      // NP/64 (64-key chunks)
#define NSTRIP 392       // NP/512 (512-key strips per pass-A block)
#define MARGIN 0.008f    // bf16-sim (<=2.5e-3) + fp16-storage (<=4.9e-4) + slack

typedef __attribute__((ext_vector_type(8))) short short8;   // 8 bf16 = 4 VGPR
typedef __attribute__((ext_vector_type(4))) float f32x4;    // MFMA acc

__device__ __forceinline__ short f2bf(float f) {
    union { float f; unsigned u; } c; c.f = f;
    unsigned u = c.u + 0x7FFFu + ((c.u >> 16) & 1u);
    return (short)(u >> 16);
}

// Guarded branch-free descending insert; constant indices after unroll.
// Precondition: nv > v[NN-1].
template <int NN>
__device__ __forceinline__ void insertg(float (&v)[NN], int (&x)[NN], float nv, int nj) {
    bool g[NN];
    #pragma unroll
    for (int i = 0; i < NN; ++i) g[i] = nv > v[i];
    #pragma unroll
    for (int i = NN - 1; i > 0; --i) {
        v[i] = g[i - 1] ? v[i - 1] : (g[i] ? nv : v[i]);
        x[i] = g[i - 1] ? x[i - 1] : (g[i] ? nj : x[i]);
    }
    v[0] = g[0] ? nv : v[0];
    x[0] = g[0] ? nj : x[0];
}

// ---------------- Kernel A: normalize queries -> fp32 qn + bf16 qbf ----------------
__global__ void qnorm_kernel(const float* __restrict__ q, float* __restrict__ qn,
                             short* __restrict__ qbf) {
    int b = blockIdx.x, t = threadIdx.x;   // 64 threads
    float v0 = q[(size_t)b * D128 + t];
    float v1 = q[(size_t)b * D128 + t + 64];
    float ss = v0 * v0 + v1 * v1;
    #pragma unroll
    for (int off = 32; off > 0; off >>= 1) ss += __shfl_xor(ss, off, 64);
    float scale = 1.0f / fmaxf(sqrtf(ss), 1e-12f);
    float a0 = v0 * scale, a1 = v1 * scale;
    qn[(size_t)b * D128 + t] = a0;
    qn[(size_t)b * D128 + t + 64] = a1;
    qbf[(size_t)b * D128 + t] = f2bf(a0);
    qbf[(size_t)b * D128 + t + 64] = f2bf(a1);
}

// ---------------- Kernel B: memory fp32 -> bf16, zero-padded to NP rows ----------------
__global__ void mconv_kernel(const float* __restrict__ mem, short* __restrict__ mbf, int N) {
    int idx = blockIdx.x * 256 + threadIdx.x;     // one short8 per thread
    if (idx >= NP * 16) return;
    int row = idx >> 4, seg = idx & 15;
    short8 out;
    if (row < N) {
        const float* p = mem + (size_t)row * D128 + seg * 8;
        #pragma unroll
        for (int i = 0; i < 8; ++i) out[i] = f2bf(p[i]);
    } else {
        #pragma unroll
        for (int i = 0; i < 8; ++i) out[i] = 0;
    }
    *(short8*)(mbf + (size_t)row * D128 + seg * 8) = out;
}

#define MFMA16(a, b, c) __builtin_amdgcn_mfma_f32_16x16x32_bf16(a, b, c, 0, 0, 0)

// ---------------- Kernel C: MFMA sweep, per-(query, 64-key-chunk) running max ----------------
// Block = 4 waves x 64 queries = 256 queries x one 512-key strip (8 rounds of 64 keys).
// Register-prefetch pipeline: global loads for round r+2 issued before computing round r+1,
// so L3 latency is hidden behind a full compute phase. Chunk-maxima are buffered in a
// 256x8 fp16 LDS tile and flushed as 16B rows -> candT[q][chunk] (transposed layout, so
// the finalize kernel reads contiguously).
__global__ __launch_bounds__(256, 3) void simtopk_max(
    const short* __restrict__ qbf, const short* __restrict__ mbf,
    _Float16* __restrict__ candT) {
    __shared__ short sK[64 * 136];        // 64 key rows, 272B stride (conflict-free)
    __shared__ _Float16 sC[256 * 8];      // per-block chunk-max tile (4 KB)
    const int strip = blockIdx.x;         // 0..391
    const int qsg = blockIdx.y;           // 0..3
    const int t = threadIdx.x, w = t >> 6, lane = t & 63;
    const int n = lane & 15, quad = lane >> 4;
    const int qbase = qsg * 256 + w * 64;

    // Resident B-frags: 4 q-tiles x 4 K-steps (64 VGPR)
    short8 bq[4][4];
    #pragma unroll
    for (int f = 0; f < 4; ++f) {
        const short* qrow = qbf + (size_t)(qbase + f * 16 + n) * D128 + quad * 8;
        #pragma unroll
        for (int s = 0; s < 4; ++s) bq[f][s] = *(const short8*)(qrow + s * 32);
    }

    const size_t k0 = (size_t)strip * 512;
    const int srow = t >> 4, scol = t & 15;         // staging row/col for this thread
    const short* gbase = mbf + (k0 + srow) * D128 + scol * 8;   // +round*64*D128; rows srow..srow+48 via j*16

    short8 r0, r1, r2, r3;
    // preload round 0
    r0 = *(const short8*)(gbase + (size_t)0 * 16 * D128);
    r1 = *(const short8*)(gbase + (size_t)1 * 16 * D128);
    r2 = *(const short8*)(gbase + (size_t)2 * 16 * D128);
    r3 = *(const short8*)(gbase + (size_t)3 * 16 * D128);
    *(short8*)(&sK[(srow +  0) * 136 + scol * 8]) = r0;
    *(short8*)(&sK[(srow + 16) * 136 + scol * 8]) = r1;
    *(short8*)(&sK[(srow + 32) * 136 + scol * 8]) = r2;
    *(short8*)(&sK[(srow + 48) * 136 + scol * 8]) = r3;
    __syncthreads();
    // issue loads for round 1 (in flight across round-0 compute)
    {
        const short* g = gbase + (size_t)1 * 64 * D128;
        r0 = *(const short8*)(g + (size_t)0 * 16 * D128);
        r1 = *(const short8*)(g + (size_t)1 * 16 * D128);
        r2 = *(const short8*)(g + (size_t)2 * 16 * D128);
        r3 = *(const short8*)(g + (size_t)3 * 16 * D128);
    }

    for (int round = 0; round < 8; ++round) {
        float m0 = -3e38f, m1 = -3e38f, m2 = -3e38f, m3 = -3e38f;
        #pragma unroll
        for (int tt = 0; tt < 4; ++tt) {
            const short* ab = &sK[(tt * 16 + n) * 136 + quad * 8];
            short8 a0 = *(const short8*)(ab);
            short8 a1 = *(const short8*)(ab + 32);
            short8 a2 = *(const short8*)(ab + 64);
            short8 a3 = *(const short8*)(ab + 96);
            f32x4 c0 = {0.f, 0.f, 0.f, 0.f}, c1 = c0, c2 = c0, c3 = c0;
            c0 = MFMA16(a0, bq[0][0], c0);
            c1 = MFMA16(a0, bq[1][0], c1);
            c2 = MFMA16(a0, bq[2][0], c2);
            c3 = MFMA16(a0, bq[3][0], c3);
            c0 = MFMA16(a1, bq[0][1], c0);
            c1 = MFMA16(a1, bq[1][1], c1);
            c2 = MFMA16(a1, bq[2][1], c2);
            c3 = MFMA16(a1, bq[3][1], c3);
            c0 = MFMA16(a2, bq[0][2], c0);
            c1 = MFMA16(a2, bq[1][2], c1);
            c2 = MFMA16(a2, bq[2][2], c2);
            c3 = MFMA16(a2, bq[3][2], c3);
            c0 = MFMA16(a3, bq[0][3], c0);
            c1 = MFMA16(a3, bq[1][3], c1);
            c2 = MFMA16(a3, bq[2][3], c2);
            c3 = MFMA16(a3, bq[3][3], c3);
            m0 = fmaxf(m0, fmaxf(fmaxf(c0[0], c0[1]), fmaxf(c0[2], c0[3])));
            m1 = fmaxf(m1, fmaxf(fmaxf(c1[0], c1[1]), fmaxf(c1[2], c1[3])));
            m2 = fmaxf(m2, fmaxf(fmaxf(c2[0], c2[1]), fmaxf(c2[2], c2[3])));
            m3 = fmaxf(m3, fmaxf(fmaxf(c3[0], c3[1]), fmaxf(c3[2], c3[3])));
        }
        // merge the 4 quads (key partitions) per query
        m0 = fmaxf(m0, __shfl_xor(m0, 16, 64)); m0 = fmaxf(m0, __shfl_xor(m0, 32, 64));
        m1 = fmaxf(m1, __shfl_xor(m1, 16, 64)); m1 = fmaxf(m1, __shfl_xor(m1, 32, 64));
        m2 = fmaxf(m2, __shfl_xor(m2, 16, 64)); m2 = fmaxf(m2, __shfl_xor(m2, 32, 64));
        m3 = fmaxf(m3, __shfl_xor(m3, 16, 64)); m3 = fmaxf(m3, __shfl_xor(m3, 32, 64));
        if (quad == 0) {
            int lr = w * 64 + n;  // local query row
            sC[(lr)      * 8 + round] = (_Float16)m0;
            sC[(lr + 16) * 8 + round] = (_Float16)m1;
            sC[(lr + 32) * 8 + round] = (_Float16)m2;
            sC[(lr + 48) * 8 + round] = (_Float16)m3;
        }
        if (round < 7) {
            __syncthreads();      // all LDS readers of this round done
            *(short8*)(&sK[(srow +  0) * 136 + scol * 8]) = r0;   // waits vmcnt
            *(short8*)(&sK[(srow + 16) * 136 + scol * 8]) = r1;
            *(short8*)(&sK[(srow + 32) * 136 + scol * 8]) = r2;
            *(short8*)(&sK[(srow + 48) * 136 + scol * 8]) = r3;
            __syncthreads();      // next tile visible
            if (round < 6) {
                const short* g = gbase + (size_t)(round + 2) * 64 * D128;
                r0 = *(const short8*)(g + (size_t)0 * 16 * D128);
                r1 = *(const short8*)(g + (size_t)1 * 16 * D128);
                r2 = *(const short8*)(g + (size_t)2 * 16 * D128);
                r3 = *(const short8*)(g + (size_t)3 * 16 * D128);
            }
        }
    }

    __syncthreads();   // sC complete
    // Flush: thread t owns local query t -> 8 contiguous fp16 (16 B) at candT[q][strip*8]
    {
        int q = qsg * 256 + t;
        short8 v = *(const short8*)(&sC[t * 8]);
        *(short8*)((short*)candT + (size_t)q * NCHUNK + strip * 8) = v;
    }
}

// ---------------- Kernel D: iterative exact selection + outputs ----------------
// One wave per query. Repeatedly recompute (fp32-exact) the chunk with the largest
// stored max; stop when next max + MARGIN <= current 5th best.
__global__ void finalize_select(const _Float16* __restrict__ candT,
                                const float* __restrict__ mem,
                                const float* __restrict__ qn,
                                const int* __restrict__ index_map,
                                const int* __restrict__ excl,
                                float* __restrict__ outR, float* __restrict__ outD,
                                float* __restrict__ outW, int N) {
    const int q = blockIdx.x, lane = threadIdx.x;
    __shared__ float sM[NCHUNK];
    __shared__ float sQ[D128];
    sQ[lane] = qn[(size_t)q * D128 + lane];
    sQ[lane + 64] = qn[(size_t)q * D128 + lane + 64];
    const _Float16* crow = candT + (size_t)q * NCHUNK;
    for (int i = lane; i < NCHUNK; i += 64)     // contiguous 6.3 KB per query
        sM[i] = (float)crow[i];
    __syncthreads();

    // per-lane pre-max over its contiguous 49 chunks (3136 = 64*49)
    float lm = -3e38f; int lc = lane * 49;
    for (int j = 0; j < 49; ++j) {
        float v = sM[lane * 49 + j];
        if (v > lm) { lm = v; lc = lane * 49 + j; }
    }

    const int exq = excl[q];
    float t5v[TOPK]; int t5i[TOPK];
    #pragma unroll
    for (int i = 0; i < TOPK; ++i) { t5v[i] = -3e38f; t5i[i] = 0; }

    for (int it = 0; it < NCHUNK; ++it) {
        // wave argmax of (lm, lc), deterministic tie-break
        float bv = lm; int bc = lc;
        #pragma unroll
        for (int off = 32; off > 0; off >>= 1) {
            float ov = __shfl_xor(bv, off, 64);
            int   oc = __shfl_xor(bc, off, 64);
            if (ov > bv || (ov == bv && oc < bc)) { bv = ov; bc = oc; }
        }
        if (bv + MARGIN <= t5v[TOPK - 1]) break;

        if (lane == 0) sM[bc] = -3e38f;
        __syncthreads();
        if (lane == bc / 49) {   // owner rescans its 49
            lm = -3e38f; lc = lane * 49;
            for (int j = 0; j < 49; ++j) {
                float v = sM[lane * 49 + j];
                if (v > lm) { lm = v; lc = lane * 49 + j; }
            }
        }

        // fp32-exact recompute of chunk bc (one key per lane)
        int key = bc * 64 + lane;
        bool valid = (key < N) && (index_map[key] != exq);
        float acc = 0.f;
        if (valid) {
            const float4* mr = (const float4*)(mem + (size_t)key * D128);
            const float4* qv4 = (const float4*)sQ;
            #pragma unroll
            for (int d = 0; d < 32; ++d) {
                float4 a = mr[d], b = qv4[d];
                acc += a.x * b.x + a.y * b.y + a.z * b.z + a.w * b.w;
            }
        }
        float v = valid ? acc : -3e38f;
        // extract up to 5 best of this chunk into running top-5
        #pragma unroll
        for (int r = 0; r < TOPK; ++r) {
            float cv = v; int ck = key;
            #pragma unroll
            for (int off = 32; off > 0; off >>= 1) {
                float ov = __shfl_xor(cv, off, 64);
                int   ok = __shfl_xor(ck, off, 64);
                if (ov > cv || (ov == cv && ok < ck)) { cv = ov; ck = ok; }
            }
            if (cv <= t5v[TOPK - 1]) break;
            insertg<TOPK>(t5v, t5i, cv, ck);
            if (key == ck) v = -3e38f;
        }
    }

    // outputs — t5v/t5i are wave-uniform, fp32-exact
    float mx = t5v[0], ex[TOPK], sum = 0.f;
    #pragma unroll
    for (int k = 0; k < TOPK; ++k) { ex[k] = __expf((t5v[k] - mx) * 10.0f); sum += ex[k]; }
    float inv = 1.0f / sum;
    if (lane == 0) {
        #pragma unroll
        for (int k = 0; k < TOPK; ++k) outW[(size_t)q * TOPK + k] = ex[k] * inv;
        outD[q] = 1.0f - t5v[0];
    }
    float r0 = 0.f, r1 = 0.f;
    #pragma unroll
    for (int k = 0; k < TOPK; ++k) {
        const float* mr = mem + (size_t)t5i[k] * D128;
        float wk = ex[k] * inv;
        r0 += wk * mr[lane];
        r1 += wk * mr[lane + 64];
    }
    float ss = r0 * r0 + r1 * r1;
    #pragma unroll
    for (int off = 32; off > 0; off >>= 1) ss += __shfl_xor(ss, off, 64);
    float scale = 1.0f / fmaxf(sqrtf(ss), 1e-12f);
    outR[(size_t)q * D128 + lane] = r0 * scale;
    outR[(size_t)q * D128 + lane + 64] = r1 * scale;
}

extern "C" void kernel_launch(void* const* d_in, const int* in_sizes, int n_in,
                              void* d_out, int out_size, void* d_ws, size_t ws_size,
                              hipStream_t stream) {
    const float* query  = (const float*)d_in[0];   // [B,128] fp32
    const float* memory = (const float*)d_in[1];   // [N,128] fp32 (pre-normalized)
    const int* index_map = (const int*)d_in[2];    // [N] int32
    const int* excl      = (const int*)d_in[3];    // [B] int32

    const int B = in_sizes[3];                     // 1024
    const int N = in_sizes[2];                     // 200000

    // Workspace:
    //   qn    fp32 [B*128]           @ 0          (512 KB)
    //   qbf   bf16 [B*128]           @ 524288     (256 KB)
    //   mbf   bf16 [NP*128]          @ 786432     (51.4 MB)
    //   candT fp16 [B=1024][NCHUNK]  @ 52166656   (6.42 MB)  total ~58.6 MB
    char* ws = (char*)d_ws;
    float*    qn    = (float*)(ws);
    short*    qbf   = (short*)(ws + 524288);
    short*    mbf   = (short*)(ws + 786432);
    _Float16* candT = (_Float16*)(ws + 52166656);

    float* outR = (float*)d_out;                   // [B,128]
    float* outD = outR + (size_t)B * D128;         // [B]
    float* outW = outD + B;                        // [B,5]

    qnorm_kernel<<<B, 64, 0, stream>>>(query, qn, qbf);
    mconv_kernel<<<(NP * 16 + 255) / 256, 256, 0, stream>>>(memory, mbf, N);
    dim3 gridC(NSTRIP, 4);
    simtopk_max<<<gridC, 256, 0, stream>>>(qbf, mbf, candT);
    finalize_select<<<B, 64, 0, stream>>>(candT, memory, qn, index_map, excl,
                                          outR, outD, outW, N);
}

// Round 5
// 283.214 us; speedup vs baseline: 12.0662x; 1.1709x over previous
//
#include <hip/hip_runtime.h>
#include <math.h>

// Shapes fixed by setup_inputs: B=1024, N=200000, D=128, K=5
#define D128 128
#define TOPK 5
#define NP 200704        // N padded to 64
#define NCH2 12544       // NP/16 : 16-key chunks
#define NSTRIP 392       // NP/512 strips (pass-A block x-dim)
#define MARGIN 0.008f    // bf16-sim (<=3.9e-3) + fp16-storage (<=4.9e-4) + slack
#define CAP 1024         // candidate-list capacity per query (overflow -> full scan)

typedef __attribute__((ext_vector_type(8))) short short8;   // 8 bf16 = 4 VGPR
typedef __attribute__((ext_vector_type(4))) float f32x4;    // MFMA acc

__device__ __forceinline__ short f2bf(float f) {
    union { float f; unsigned u; } c; c.f = f;
    unsigned u = c.u + 0x7FFFu + ((c.u >> 16) & 1u);
    return (short)(u >> 16);
}

// Guarded branch-free descending insert (val+idx). Precondition: nv > v[NN-1].
template <int NN>
__device__ __forceinline__ void insertg(float (&v)[NN], int (&x)[NN], float nv, int nj) {
    bool g[NN];
    #pragma unroll
    for (int i = 0; i < NN; ++i) g[i] = nv > v[i];
    #pragma unroll
    for (int i = NN - 1; i > 0; --i) {
        v[i] = g[i - 1] ? v[i - 1] : (g[i] ? nv : v[i]);
        x[i] = g[i - 1] ? x[i - 1] : (g[i] ? nj : x[i]);
    }
    v[0] = g[0] ? nv : v[0];
    x[0] = g[0] ? nj : x[0];
}
// Values-only variant. Precondition: nv > v[NN-1].
template <int NN>
__device__ __forceinline__ void insertv(float (&v)[NN], float nv) {
    bool g[NN];
    #pragma unroll
    for (int i = 0; i < NN; ++i) g[i] = nv > v[i];
    #pragma unroll
    for (int i = NN - 1; i > 0; --i)
        v[i] = g[i - 1] ? v[i - 1] : (g[i] ? nv : v[i]);
    v[0] = g[0] ? nv : v[0];
}

// ---------------- Kernel A: normalize queries -> fp32 qn + bf16 qbf ----------------
__global__ void qnorm_kernel(const float* __restrict__ q, float* __restrict__ qn,
                             short* __restrict__ qbf) {
    int b = blockIdx.x, t = threadIdx.x;   // 64 threads
    float v0 = q[(size_t)b * D128 + t];
    float v1 = q[(size_t)b * D128 + t + 64];
    float ss = v0 * v0 + v1 * v1;
    #pragma unroll
    for (int off = 32; off > 0; off >>= 1) ss += __shfl_xor(ss, off, 64);
    float scale = 1.0f / fmaxf(sqrtf(ss), 1e-12f);
    float a0 = v0 * scale, a1 = v1 * scale;
    qn[(size_t)b * D128 + t] = a0;
    qn[(size_t)b * D128 + t + 64] = a1;
    qbf[(size_t)b * D128 + t] = f2bf(a0);
    qbf[(size_t)b * D128 + t + 64] = f2bf(a1);
}

// ---------------- Kernel B: memory fp32 -> bf16, zero-padded to NP rows ----------------
__global__ void mconv_kernel(const float* __restrict__ mem, short* __restrict__ mbf, int N) {
    int idx = blockIdx.x * 256 + threadIdx.x;     // one short8 per thread
    if (idx >= NP * 16) return;
    int row = idx >> 4, seg = idx & 15;
    short8 out;
    if (row < N) {
        const float* p = mem + (size_t)row * D128 + seg * 8;
        #pragma unroll
        for (int i = 0; i < 8; ++i) out[i] = f2bf(p[i]);
    } else {
        #pragma unroll
        for (int i = 0; i < 8; ++i) out[i] = 0;
    }
    *(short8*)(mbf + (size_t)row * D128 + seg * 8) = out;
}

#define MFMA16(a, b, c) __builtin_amdgcn_mfma_f32_16x16x32_bf16(a, b, c, 0, 0, 0)

// ---------------- Kernel C: MFMA sweep, per-(query, 16-key-chunk) max ----------------
// Block = 4 waves x 64 queries = 256 queries x one 512-key strip (8 rounds of 64 keys,
// each round = 4 MFMA tiles = 4 chunks). Register-prefetch pipeline (distance 2).
// Each MFMA tile's C-fragment max is reduced across quads and buffered in sC
// (stride 40 fp16: 16B-aligned rows, 2-way LDS aliasing = free), then flushed as
// 64 B contiguous rows -> candT[q][chunk].
__global__ __launch_bounds__(256, 3) void simtopk_max(
    const short* __restrict__ qbf, const short* __restrict__ mbf,
    _Float16* __restrict__ candT) {
    __shared__ short sK[64 * 136];        // 17.4 KB key tile (272B stride)
    __shared__ _Float16 sC[256 * 40];     // 20 KB chunk-max tile (32 used of 40)
    const int strip = blockIdx.x;         // 0..391
    const int qsg = blockIdx.y;           // 0..3
    const int t = threadIdx.x, w = t >> 6, lane = t & 63;
    const int n = lane & 15, quad = lane >> 4;
    const int qbase = qsg * 256 + w * 64;

    // Resident B-frags: 4 q-tiles x 4 K-steps (64 VGPR)
    short8 bq[4][4];
    #pragma unroll
    for (int f = 0; f < 4; ++f) {
        const short* qrow = qbf + (size_t)(qbase + f * 16 + n) * D128 + quad * 8;
        #pragma unroll
        for (int s = 0; s < 4; ++s) bq[f][s] = *(const short8*)(qrow + s * 32);
    }

    const size_t k0 = (size_t)strip * 512;
    const int srow = t >> 4, scol = t & 15;
    const short* gbase = mbf + (k0 + srow) * D128 + scol * 8;

    short8 r0, r1, r2, r3;
    r0 = *(const short8*)(gbase + (size_t)0 * 16 * D128);
    r1 = *(const short8*)(gbase + (size_t)1 * 16 * D128);
    r2 = *(const short8*)(gbase + (size_t)2 * 16 * D128);
    r3 = *(const short8*)(gbase + (size_t)3 * 16 * D128);
    *(short8*)(&sK[(srow +  0) * 136 + scol * 8]) = r0;
    *(short8*)(&sK[(srow + 16) * 136 + scol * 8]) = r1;
    *(short8*)(&sK[(srow + 32) * 136 + scol * 8]) = r2;
    *(short8*)(&sK[(srow + 48) * 136 + scol * 8]) = r3;
    __syncthreads();
    {
        const short* g = gbase + (size_t)1 * 64 * D128;
        r0 = *(const short8*)(g + (size_t)0 * 16 * D128);
        r1 = *(const short8*)(g + (size_t)1 * 16 * D128);
        r2 = *(const short8*)(g + (size_t)2 * 16 * D128);
        r3 = *(const short8*)(g + (size_t)3 * 16 * D128);
    }

    for (int round = 0; round < 8; ++round) {
        #pragma unroll
        for (int tt = 0; tt < 4; ++tt) {
            const short* ab = &sK[(tt * 16 + n) * 136 + quad * 8];
            short8 a0 = *(const short8*)(ab);
            short8 a1 = *(const short8*)(ab + 32);
            short8 a2 = *(const short8*)(ab + 64);
            short8 a3 = *(const short8*)(ab + 96);
            f32x4 c0 = {0.f, 0.f, 0.f, 0.f}, c1 = c0, c2 = c0, c3 = c0;
            c0 = MFMA16(a0, bq[0][0], c0);
            c1 = MFMA16(a0, bq[1][0], c1);
            c2 = MFMA16(a0, bq[2][0], c2);
            c3 = MFMA16(a0, bq[3][0], c3);
            c0 = MFMA16(a1, bq[0][1], c0);
            c1 = MFMA16(a1, bq[1][1], c1);
            c2 = MFMA16(a1, bq[2][1], c2);
            c3 = MFMA16(a1, bq[3][1], c3);
            c0 = MFMA16(a2, bq[0][2], c0);
            c1 = MFMA16(a2, bq[1][2], c1);
            c2 = MFMA16(a2, bq[2][2], c2);
            c3 = MFMA16(a2, bq[3][2], c3);
            c0 = MFMA16(a3, bq[0][3], c0);
            c1 = MFMA16(a3, bq[1][3], c1);
            c2 = MFMA16(a3, bq[2][3], c2);
            c3 = MFMA16(a3, bq[3][3], c3);
            // per-chunk (=per-tile) max for each of the 4 query frags
            float m0 = fmaxf(fmaxf(c0[0], c0[1]), fmaxf(c0[2], c0[3]));
            float m1 = fmaxf(fmaxf(c1[0], c1[1]), fmaxf(c1[2], c1[3]));
            float m2 = fmaxf(fmaxf(c2[0], c2[1]), fmaxf(c2[2], c2[3]));
            float m3 = fmaxf(fmaxf(c3[0], c3[1]), fmaxf(c3[2], c3[3]));
            m0 = fmaxf(m0, __shfl_xor(m0, 16, 64)); m0 = fmaxf(m0, __shfl_xor(m0, 32, 64));
            m1 = fmaxf(m1, __shfl_xor(m1, 16, 64)); m1 = fmaxf(m1, __shfl_xor(m1, 32, 64));
            m2 = fmaxf(m2, __shfl_xor(m2, 16, 64)); m2 = fmaxf(m2, __shfl_xor(m2, 32, 64));
            m3 = fmaxf(m3, __shfl_xor(m3, 16, 64)); m3 = fmaxf(m3, __shfl_xor(m3, 32, 64));
            // quad g stores frag g: local query = w*64 + quad*16 + n, col = round*4+tt
            float msel = (quad == 0) ? m0 : (quad == 1) ? m1 : (quad == 2) ? m2 : m3;
            sC[(w * 64 + quad * 16 + n) * 40 + round * 4 + tt] = (_Float16)msel;
        }
        if (round < 7) {
            __syncthreads();
            *(short8*)(&sK[(srow +  0) * 136 + scol * 8]) = r0;
            *(short8*)(&sK[(srow + 16) * 136 + scol * 8]) = r1;
            *(short8*)(&sK[(srow + 32) * 136 + scol * 8]) = r2;
            *(short8*)(&sK[(srow + 48) * 136 + scol * 8]) = r3;
            __syncthreads();
            if (round < 6) {
                const short* g = gbase + (size_t)(round + 2) * 64 * D128;
                r0 = *(const short8*)(g + (size_t)0 * 16 * D128);
                r1 = *(const short8*)(g + (size_t)1 * 16 * D128);
                r2 = *(const short8*)(g + (size_t)2 * 16 * D128);
                r3 = *(const short8*)(g + (size_t)3 * 16 * D128);
            }
        }
    }

    __syncthreads();
    // Flush: thread t = local query t -> 32 fp16 (64 B) at candT[q][strip*32]
    {
        int q = qsg * 256 + t;
        short* dst = (short*)candT + (size_t)q * NCH2 + strip * 32;
        #pragma unroll
        for (int j = 0; j < 4; ++j)
            *(short8*)(dst + j * 8) = *(const short8*)(&sC[t * 40 + j * 8]);
    }
}

// ---------------- Kernel D: threshold + batched exact rescore + outputs ----------------
// One 256-thread block per query.
//   P1: thr6 = 6th-largest chunk max  ->  any top-5 key's chunk has cmax >= thr6-2*MARGIN
//       (6 distinct chunks give >=6 keys with exact sim >= thr6-MARGIN; >=5 survive
//        exclusion, so t5_exact >= thr6-MARGIN; top-5 key: cmax >= sim-MARGIN >= thr).
//   P2: build candidate chunk list (LDS atomic append; overflow -> full scan).
//   P3: rescore candidates in parallel, fp32-exact: lane = one key; 16 chunks/round.
//   P4: merge per-thread top-5 -> block top-5 -> softmax/gather/normalize.
__global__ __launch_bounds__(256, 4) void finalize_batch(
    const _Float16* __restrict__ candT, const float* __restrict__ mem,
    const float* __restrict__ qn, const int* __restrict__ index_map,
    const int* __restrict__ excl,
    float* __restrict__ outR, float* __restrict__ outD, float* __restrict__ outW, int N) {
    const int q = blockIdx.x, t = threadIdx.x;
    const int w = t >> 6, lane = t & 63;

    __shared__ _Float16 sM[NCH2];     // 25.1 KB
    __shared__ float sQ[D128];
    __shared__ unsigned short sList[CAP];
    __shared__ int sCnt, sOv;
    __shared__ float sThr;
    __shared__ float sMrg[4 * 6];
    __shared__ float sWv[4 * TOPK];
    __shared__ int   sWk[4 * TOPK];
    __shared__ float sW[TOPK];
    __shared__ int   sJ[TOPK];

    if (t < 128) sQ[t] = qn[(size_t)q * D128 + t];
    if (t == 0) { sCnt = 0; sOv = 0; }
    {
        const short* crow = (const short*)candT + (size_t)q * NCH2;
        for (int i = t; i < NCH2 / 8; i += 256)
            *(short8*)(&sM[i * 8]) = *(const short8*)(crow + i * 8);
    }
    __syncthreads();

    // ---- P1: per-thread top-6 over strided chunks, then wave+block merge ----
    float pv[6];
    #pragma unroll
    for (int i = 0; i < 6; ++i) pv[i] = -3e38f;
    for (int i = t; i < NCH2; i += 256) {
        float v = (float)sM[i];
        if (v > pv[5]) insertv<6>(pv, v);
    }
    #pragma unroll
    for (int r = 0; r < 6; ++r) {
        float bv = pv[0];
        #pragma unroll
        for (int off = 32; off > 0; off >>= 1) bv = fmaxf(bv, __shfl_xor(bv, off, 64));
        int ml = (pv[0] == bv) ? lane : 64;
        #pragma unroll
        for (int off = 32; off > 0; off >>= 1) ml = min(ml, __shfl_xor(ml, off, 64));
        if (lane == ml) {
            #pragma unroll
            for (int i = 0; i < 5; ++i) pv[i] = pv[i + 1];
            pv[5] = -3e38f;
        }
        if (lane == 0) sMrg[w * 6 + r] = bv;
    }
    __syncthreads();
    if (t == 0) {
        float b6[6];
        #pragma unroll
        for (int i = 0; i < 6; ++i) b6[i] = -3e38f;
        for (int j = 0; j < 24; ++j) {
            float v = sMrg[j];
            if (v > b6[5]) insertv<6>(b6, v);
        }
        sThr = b6[5] - 2.0f * MARGIN;
    }
    __syncthreads();

    // ---- P2: candidate list ----
    const float thr = sThr;
    for (int i = t; i < NCH2; i += 256) {
        if ((float)sM[i] >= thr) {
            int p = atomicAdd(&sCnt, 1);
            if (p < CAP) sList[p] = (unsigned short)i; else sOv = 1;
        }
    }
    __syncthreads();
    const int ov = sOv;
    const int cnt = ov ? NCH2 : min(sCnt, CAP);

    // ---- P3: batched fp32-exact rescore ----
    const int exq = excl[q];
    float tv[TOPK]; int ti[TOPK];
    #pragma unroll
    for (int i = 0; i < TOPK; ++i) { tv[i] = -3e38f; ti[i] = -1; }
    const int rounds = (cnt + 15) >> 4;
    for (int r = 0; r < rounds; ++r) {
        int slot = r * 16 + (t >> 4);
        int ch = (slot < cnt) ? (ov ? slot : (int)sList[slot]) : -1;
        int key = ch * 16 + (t & 15);
        float v = -3e38f;
        if (ch >= 0 && key < N && index_map[key] != exq) {
            const float4* mr = (const float4*)(mem + (size_t)key * D128);
            const float4* qv = (const float4*)sQ;
            float acc = 0.f;
            #pragma unroll
            for (int d = 0; d < 32; ++d) {
                float4 a = mr[d], b = qv[d];
                acc += a.x * b.x + a.y * b.y + a.z * b.z + a.w * b.w;
            }
            v = acc;
        }
        if (v > tv[TOPK - 1]) insertg<TOPK>(tv, ti, v, key);
    }

    // ---- P4: wave extraction (tie-break: smaller key), then block merge ----
    #pragma unroll
    for (int r = 0; r < TOPK; ++r) {
        float bv = tv[0]; int bk = ti[0];
        #pragma unroll
        for (int off = 32; off > 0; off >>= 1) {
            float ovv = __shfl_xor(bv, off, 64);
            int   okk = __shfl_xor(bk, off, 64);
            if (ovv > bv || (ovv == bv && (unsigned)okk < (unsigned)bk)) { bv = ovv; bk = okk; }
        }
        if (tv[0] == bv && ti[0] == bk) {
            #pragma unroll
            for (int i = 0; i < TOPK - 1; ++i) { tv[i] = tv[i + 1]; ti[i] = ti[i + 1]; }
            tv[TOPK - 1] = -3e38f; ti[TOPK - 1] = -1;
        }
        if (lane == 0) { sWv[w * TOPK + r] = bv; sWk[w * TOPK + r] = bk; }
    }
    __syncthreads();
    if (t == 0) {
        float bv[TOPK]; int bi[TOPK];
        #pragma unroll
        for (int i = 0; i < TOPK; ++i) { bv[i] = -3e38f; bi[i] = -1; }
        for (int j = 0; j < 4 * TOPK; ++j) {
            float v = sWv[j];
            if (v > bv[TOPK - 1]) insertg<TOPK>(bv, bi, v, sWk[j]);
        }
        float m = bv[0], ex[TOPK], sum = 0.f;
        #pragma unroll
        for (int k = 0; k < TOPK; ++k) { ex[k] = __expf((bv[k] - m) * 10.0f); sum += ex[k]; }
        float inv = 1.0f / sum;
        #pragma unroll
        for (int k = 0; k < TOPK; ++k) {
            float wk = ex[k] * inv;
            sW[k] = wk; sJ[k] = bi[k];
            outW[(size_t)q * TOPK + k] = wk;
        }
        outD[q] = 1.0f - bv[0];
    }
    __syncthreads();
    if (t < 64) {
        float r0 = 0.f, r1 = 0.f;
        #pragma unroll
        for (int k = 0; k < TOPK; ++k) {
            const float* mr = mem + (size_t)sJ[k] * D128;
            r0 += sW[k] * mr[t];
            r1 += sW[k] * mr[t + 64];
        }
        float ss = r0 * r0 + r1 * r1;
        #pragma unroll
        for (int off = 32; off > 0; off >>= 1) ss += __shfl_xor(ss, off, 64);
        float scale = 1.0f / fmaxf(sqrtf(ss), 1e-12f);
        outR[(size_t)q * D128 + t]      = r0 * scale;
        outR[(size_t)q * D128 + t + 64] = r1 * scale;
    }
}

extern "C" void kernel_launch(void* const* d_in, const int* in_sizes, int n_in,
                              void* d_out, int out_size, void* d_ws, size_t ws_size,
                              hipStream_t stream) {
    const float* query  = (const float*)d_in[0];   // [B,128] fp32
    const float* memory = (const float*)d_in[1];   // [N,128] fp32 (pre-normalized)
    const int* index_map = (const int*)d_in[2];    // [N] int32
    const int* excl      = (const int*)d_in[3];    // [B] int32

    const int B = in_sizes[3];                     // 1024
    const int N = in_sizes[2];                     // 200000

    // Workspace:
    //   qn    fp32 [B*128]         @ 0          (512 KB)
    //   qbf   bf16 [B*128]         @ 524288     (256 KB)
    //   mbf   bf16 [NP*128]        @ 786432     (51.4 MB)
    //   candT fp16 [B][NCH2]       @ 52166656   (25.7 MB)   total ~77.9 MB
    char* ws = (char*)d_ws;
    float*    qn    = (float*)(ws);
    short*    qbf   = (short*)(ws + 524288);
    short*    mbf   = (short*)(ws + 786432);
    _Float16* candT = (_Float16*)(ws + 52166656);

    float* outR = (float*)d_out;                   // [B,128]
    float* outD = outR + (size_t)B * D128;         // [B]
    float* outW = outD + B;                        // [B,5]

    qnorm_kernel<<<B, 64, 0, stream>>>(query, qn, qbf);
    mconv_kernel<<<(NP * 16 + 255) / 256, 256, 0, stream>>>(memory, mbf, N);
    dim3 gridC(NSTRIP, 4);
    simtopk_max<<<gridC, 256, 0, stream>>>(qbf, mbf, candT);
    finalize_batch<<<B, 256, 0, stream>>>(candT, memory, qn, index_map, excl,
                                          outR, outD, outW, N);
}